// Round 1
// 328.159 us; speedup vs baseline: 1.0702x; 1.0702x over previous
//
#include <hip/hip_runtime.h>
#include <hip/hip_bf16.h>
#include <math.h>

#define BATCH 2
#define C 192
#define H 128
#define W 256
#define HEADS 6
#define HD 32
#define HW (H * W)      // 32768
#define C3 (3 * C)      // 576
#define NPX (BATCH * HW)  // 65536

typedef unsigned short ushort_t;
using bf16x8 = __attribute__((ext_vector_type(8))) short;
using f32x4  = __attribute__((ext_vector_type(4))) float;

static __device__ __forceinline__ float bfbits2f(ushort_t u) {
    return __uint_as_float(((unsigned)u) << 16);
}
static __device__ __forceinline__ ushort_t f2bfbits(float f) {
    __hip_bfloat16 h = __float2bfloat16(f);
    return *reinterpret_cast<ushort_t*>(&h);
}

// ---------------------------------------------------------------------------
// prep_w: fp32 -> bf16 weights; q-rows of w_qkv pre-scaled by 32^-0.5*log2(e)
// (softmax computed in base-2; exp2 saves the per-element ln2 multiply).
// ---------------------------------------------------------------------------
__global__ __launch_bounds__(256) void prep_w_kernel(
    const float* __restrict__ wq, const float* __restrict__ wg,
    const float* __restrict__ wp, const float* __restrict__ wo,
    ushort_t* __restrict__ dst)
{
    const int i = blockIdx.x * 256 + threadIdx.x;   // float4 index, < 55296
    const float* src; int off, base;
    if (i < 27648)      { src = wq; off = i;         base = 0; }
    else if (i < 36864) { src = wg; off = i - 27648; base = 110592; }
    else if (i < 46080) { src = wp; off = i - 36864; base = 147456; }
    else                { src = wo; off = i - 46080; base = 184320; }
    float4 v = ((const float4*)src)[off];
    if (i < 9216) {   // w_qkv rows 0..191 (the q projection)
        const float sc = 0.25503488f;   // 32^-0.5 * log2(e)
        v.x *= sc; v.y *= sc; v.z *= sc; v.w *= sc;
    }
    ushort4 o;
    o.x = f2bfbits(v.x); o.y = f2bfbits(v.y);
    o.z = f2bfbits(v.z); o.w = f2bfbits(v.w);
    *(ushort4*)(dst + base + off * 4) = o;
}

// ---------------------------------------------------------------------------
// transpose_x: x [B][192][HW] f32 -> x_t [B*HW][192] bf16 (pixel-major).
// ---------------------------------------------------------------------------
__global__ __launch_bounds__(256) void transpose_x_kernel(
    const float* __restrict__ x, ushort_t* __restrict__ xt)
{
    __shared__ uint Xs[64 * 97];   // 24.8 KB
    const int p0 = blockIdx.x * 64;
    const int b  = p0 >> 15, hw0 = p0 & (HW - 1);
    const int t  = threadIdx.x;

    {
        const int px = t & 63, g = t >> 6;
        const float* xb = x + (size_t)b * C * HW + hw0 + px;
#pragma unroll
        for (int i = 0; i < 24; ++i) {
            const int cp = g + i * 4;   // channel pair 0..95
            const float v0 = xb[(size_t)(2 * cp) * HW];
            const float v1 = xb[(size_t)(2 * cp + 1) * HW];
            Xs[px * 97 + cp] = (uint)f2bfbits(v0) | ((uint)f2bfbits(v1) << 16);
        }
    }
    __syncthreads();
    {
        const int px = t >> 2, grp = t & 3;
        uint* dst = (uint*)(xt + (size_t)(p0 + px) * C) + grp * 24;
        const uint* s = &Xs[px * 97 + grp * 24];
#pragma unroll
        for (int i = 0; i < 6; ++i) {
            uint4 u;
            u.x = s[i * 4 + 0]; u.y = s[i * 4 + 1];
            u.z = s[i * 4 + 2]; u.w = s[i * 4 + 3];
            *(uint4*)(dst + i * 4) = u;
        }
    }
}

// ---------------------------------------------------------------------------
// MFMA conv1x1 GEMM v2 (unchanged). Block: 4 waves; tile M=64 x N=512, K=192.
// ---------------------------------------------------------------------------
template <int MODE, int OUTKIND, int MT>
__global__ __launch_bounds__(256) void conv_mfma_kernel(
    const ushort_t* __restrict__ in_t, const ushort_t* __restrict__ w_bf,
    void* __restrict__ outp, const ushort_t* __restrict__ gate, int ostride)
{
    const int lin = blockIdx.x;
    const int xcd = lin & 7;
    const int jj  = lin >> 3;
    const int pin = jj / MT;            // 0..15
    const int m   = jj - pin * MT;      // 0..MT-1
    const int m0  = m * 64;
    const int p0  = (xcd * 16 + pin) * 512;

    const int t  = threadIdx.x;
    const int wv = t >> 6, lane = t & 63, quad = lane >> 4, l16 = lane & 15;

    __shared__ ushort_t As[64 * 200];   // 25.6 KB
    {
        const int row = t >> 2, cg = (t & 3) * 48;
        const ushort_t* src = w_bf + (size_t)(m0 + row) * C + cg;
        ushort_t* dst = &As[row * 200 + cg];
#pragma unroll
        for (int i = 0; i < 6; ++i)
            *(bf16x8*)(dst + i * 8) = *(const bf16x8*)(src + i * 8);
    }
    __syncthreads();

    f32x4 acc[4][8];
#pragma unroll
    for (int rt = 0; rt < 4; ++rt)
#pragma unroll
        for (int ct = 0; ct < 8; ++ct) acc[rt][ct] = f32x4{0.f, 0.f, 0.f, 0.f};

    const ushort_t* bp = in_t + (size_t)(p0 + wv * 128 + l16) * C + quad * 8;

    bf16x8 bF[8], bFn[8];
#pragma unroll
    for (int ct = 0; ct < 8; ++ct)
        bF[ct] = *(const bf16x8*)(bp + (size_t)(ct * 16) * C);

#pragma unroll
    for (int ks = 0; ks < 6; ++ks) {
        if (ks < 5) {
#pragma unroll
            for (int ct = 0; ct < 8; ++ct)
                bFn[ct] = *(const bf16x8*)(bp + (size_t)(ct * 16) * C +
                                           (ks + 1) * 32);
        }
        bf16x8 aF[4];
#pragma unroll
        for (int rt = 0; rt < 4; ++rt)
            aF[rt] = *(const bf16x8*)&As[(rt * 16 + l16) * 200 + quad * 8 + ks * 32];
#pragma unroll
        for (int rt = 0; rt < 4; ++rt)
#pragma unroll
            for (int ct = 0; ct < 8; ++ct)
                acc[rt][ct] = __builtin_amdgcn_mfma_f32_16x16x32_bf16(
                    aF[rt], bF[ct], acc[rt][ct], 0, 0, 0);
#pragma unroll
        for (int ct = 0; ct < 8; ++ct) bF[ct] = bFn[ct];
    }

    // ---- epilogue ----
#pragma unroll
    for (int rt = 0; rt < 4; ++rt)
#pragma unroll
        for (int ct = 0; ct < 8; ++ct) {
            f32x4 v = acc[rt][ct];
            if (MODE == 1) {
#pragma unroll
                for (int r = 0; r < 4; ++r)
                    v[r] = v[r] / (1.f + __expf(-v[r]));
            }
            acc[rt][ct] = v;
        }

    if constexpr (OUTKIND == 0) {
        ushort_t* ob = (ushort_t*)outp;
#pragma unroll
        for (int rt = 0; rt < 4; ++rt)
#pragma unroll
            for (int ct = 0; ct < 8; ++ct) {
                const int px = p0 + wv * 128 + ct * 16 + l16;
                const int ch = m0 + rt * 16 + quad * 4;
                f32x4 v = acc[rt][ct];
                if (MODE == 2) {
                    const ushort4 g = *(const ushort4*)(gate + (size_t)px * C + ch);
                    v[0] *= bfbits2f(g.x); v[1] *= bfbits2f(g.y);
                    v[2] *= bfbits2f(g.z); v[3] *= bfbits2f(g.w);
                }
                ushort4 o;
                o.x = f2bfbits(v[0]); o.y = f2bfbits(v[1]);
                o.z = f2bfbits(v[2]); o.w = f2bfbits(v[3]);
                *(ushort4*)(ob + (size_t)px * ostride + ch) = o;
            }
    } else {
        const int bb = p0 >> 15;
        const int hwb = (p0 & (HW - 1)) + wv * 128;
        float* ob = (float*)outp + ((size_t)bb * C + m0) * HW + hwb;
#pragma unroll
        for (int rt = 0; rt < 4; ++rt)
#pragma unroll
            for (int ct = 0; ct < 8; ++ct) {
                const f32x4 v = acc[rt][ct];
#pragma unroll
                for (int r = 0; r < 4; ++r)
                    ob[(size_t)(rt * 16 + quad * 4 + r) * HW + ct * 16 + l16] = v[r];
            }
    }
}

// ---------------------------------------------------------------------------
// depthwise 3x3, pixel-major (unchanged).
// ---------------------------------------------------------------------------
__global__ __launch_bounds__(256) void dwconv3x3_px_kernel(
    const ushort_t* __restrict__ tin, const float* __restrict__ wd,
    ushort_t* __restrict__ out)
{
    __shared__ float wloc[576];
    const int cb  = blockIdx.y;
    const int tid = threadIdx.x;
    if (tid < 144)
        *(float4*)&wloc[tid * 4] = *(const float4*)(wd + cb * 576 + tid * 4);
    __syncthreads();

    const int chloc = (tid & 7) * 8;
    const int px = blockIdx.x * 128 + (tid >> 3) * 4;
    const int x0 = px & (W - 1);
    const int y  = (px >> 8) & (H - 1);

    const ushort_t* tb = tin + (size_t)px * C3 + cb * 64 + chloc;

    float acc[4][8];
#pragma unroll
    for (int i = 0; i < 4; ++i)
#pragma unroll
        for (int k = 0; k < 8; ++k) acc[i][k] = 0.f;

#pragma unroll
    for (int dy = -1; dy <= 1; ++dy) {
        const int yy = y + dy;
        if (yy < 0 || yy >= H) continue;
        const ushort_t* rp = tb + (ptrdiff_t)dy * W * C3;

        float f[6][8];
#pragma unroll
        for (int d = 0; d < 6; ++d) {
            const int xx = x0 + d - 1;
            if (xx < 0 || xx >= W) {
#pragma unroll
                for (int k = 0; k < 8; ++k) f[d][k] = 0.f;
            } else {
                const bf16x8 v = *(const bf16x8*)(rp + (ptrdiff_t)(d - 1) * C3);
#pragma unroll
                for (int k = 0; k < 8; ++k) f[d][k] = bfbits2f((ushort_t)v[k]);
            }
        }
#pragma unroll
        for (int k = 0; k < 8; ++k) {
            const float* wk = &wloc[(chloc + k) * 9 + (dy + 1) * 3];
            const float w0 = wk[0], w1 = wk[1], w2 = wk[2];
#pragma unroll
            for (int i = 0; i < 4; ++i)
                acc[i][k] += f[i][k] * w0 + f[i + 1][k] * w1 + f[i + 2][k] * w2;
        }
    }

    ushort_t* ob = out + (size_t)px * C3 + cb * 64 + chloc;
#pragma unroll
    for (int i = 0; i < 4; ++i) {
        bf16x8 o;
#pragma unroll
        for (int k = 0; k < 8; ++k) o[k] = (short)f2bfbits(acc[i][k]);
        *(bf16x8*)(ob + (size_t)i * C3) = o;
    }
}

// ---------------------------------------------------------------------------
// MFMA attention v2 — occupancy-oriented rewrite.
//  * Swapped QK^T: S^T = mfma(K_frag, Q_frag, bias^T). A and B fragments of
//    16x16x32 share the same register layout (l16 -> m/n, quad*8 -> k), so
//    the Q fragment loads straight from global and works as the B operand.
//    Lane then holds P for a FIXED attention row i = rt*16+l16: softmax sum
//    is lane-local (+2 shfl_xor), P packs to bf16 pairs -> 2x ds_write_b64
//    per (n,rt) instead of 16x ds_write_b16 (4x fewer LDS writes, balanced
//    banks at stride 40).
//  * No Q/K LDS staging: Q frags direct; K frags per-n from global with a
//    1-deep prefetch (16x64B segments, L2-hot, 4x reuse across waves).
//  * Softmax in base 2: q-rows and rpb pre-scaled by log2(e); p = v_exp_f32.
//  * LDS: Vt 16896 + Pb 20480 + rb 2048 = 39424 B -> 4 blocks/CU (was
//    61952 -> 2 blocks/CU). __launch_bounds__(256,4) caps VGPR at 128.
// ---------------------------------------------------------------------------
__global__ __launch_bounds__(256, 4) void attention_mfma_kernel(
    const ushort_t* __restrict__ qkv, const float* __restrict__ rpb,
    ushort_t* __restrict__ att)
{
    const int y    = blockIdx.x;
    const int head = blockIdx.y;
    const int b    = blockIdx.z;
    const int t    = threadIdx.x;
    const int wv   = t >> 6;
    const int lane = t & 63;
    const int quad = lane >> 4;
    const int l16  = lane & 15;

    __shared__ __align__(16) char smem[39424];
    ushort_t* Vt = (ushort_t*)smem;               // [32][264]  = 16896 B
    ushort_t* Pb = (ushort_t*)(smem + 16896);     // [4][64][40]= 20480 B
    ushort_t* rb = (ushort_t*)(smem + 37376);     // [2][512]   =  2048 B
    float*    Ol = (float*)smem;                  // [32][257] epilogue overlay

    const size_t rowbase = ((size_t)b * HW + (size_t)y * W) * C3;
    const ushort_t* qbase = qkv + rowbase + head * HD + quad * 8;
    const ushort_t* kbase = qbase + C;

    // ---- stage V transposed into LDS; build base-2 rpb table (2 copies) ----
    {
        const ushort_t* rowp = qkv + rowbase + (size_t)t * C3 + head * HD;
        bf16x8 vfr[4];
#pragma unroll
        for (int g = 0; g < 4; ++g)
            vfr[g] = *(const bf16x8*)(rowp + 2 * C + g * 8);
#pragma unroll
        for (int g = 0; g < 4; ++g)
#pragma unroll
            for (int k = 0; k < 8; ++k)
                Vt[(g * 8 + k) * 264 + t] = (ushort_t)vfr[g][k];
    }
    {
        const float LOG2E = 1.4426950408889634f;
#pragma unroll
        for (int s2 = 0; s2 < 2; ++s2)
#pragma unroll
            for (int pp = 0; pp < 2; ++pp) {
                const int k = pp * 256 + t;
                const int src = k + s2;
                rb[s2 * 512 + k] =
                    f2bfbits(src <= 510 ? rpb[src * HEADS + head] * LOG2E : 0.f);
            }
    }

    // Q fragments (B-operand layout) direct from global; first K fragment.
    bf16x8 aQ[4];
#pragma unroll
    for (int rt = 0; rt < 4; ++rt)
        aQ[rt] = *(const bf16x8*)(qbase + (size_t)(wv * 64 + rt * 16 + l16) * C3);
    bf16x8 bK = *(const bf16x8*)(kbase + (size_t)l16 * C3);

    __syncthreads();

    ushort_t* PbW = Pb + wv * 2560;
    float lsum[4] = {0.f, 0.f, 0.f, 0.f};
    f32x4 o_acc[4][2];
#pragma unroll
    for (int rt = 0; rt < 4; ++rt)
#pragma unroll
        for (int ct = 0; ct < 2; ++ct)
            o_acc[rt][ct] = f32x4{0.f, 0.f, 0.f, 0.f};

    const int ibase = wv * 64 + l16 + 255 - quad * 4;

    for (int c2 = 0; c2 < 8; ++c2) {
#pragma unroll
        for (int half = 0; half < 2; ++half) {
            const int n  = c2 * 2 + half;
            const int nn = (n < 15) ? n + 1 : 15;
            const bf16x8 bKn =
                *(const bf16x8*)(kbase + (size_t)(nn * 16 + l16) * C3);
#pragma unroll
            for (int rt = 0; rt < 4; ++rt) {
                // bias^T: idx = i - j + 255 = (ibase + rt*16 - n*16) - reg
                const int a  = ibase + rt * 16 - n * 16 - 3;  // 0..507
                const int s2 = a & 1;
                const uint* tp = (const uint*)(rb + s2 * 512 + (a - s2));
                const uint u0 = tp[0], u1 = tp[1];  // rpb2[a..a+3]
                f32x4 s;
                s[0] = __uint_as_float(u1 & 0xffff0000u);
                s[1] = __uint_as_float(u1 << 16);
                s[2] = __uint_as_float(u0 & 0xffff0000u);
                s[3] = __uint_as_float(u0 << 16);
                s = __builtin_amdgcn_mfma_f32_16x16x32_bf16(bK, aQ[rt], s, 0, 0, 0);
                const float p0 = __builtin_amdgcn_exp2f(s[0]);
                const float p1 = __builtin_amdgcn_exp2f(s[1]);
                const float p2 = __builtin_amdgcn_exp2f(s[2]);
                const float p3 = __builtin_amdgcn_exp2f(s[3]);
                lsum[rt] += (p0 + p1) + (p2 + p3);
                uint2 dd;
                dd.x = (uint)f2bfbits(p0) | ((uint)f2bfbits(p1) << 16);
                dd.y = (uint)f2bfbits(p2) | ((uint)f2bfbits(p3) << 16);
                *(uint2*)&PbW[(rt * 16 + l16) * 40 + half * 16 + quad * 4] = dd;
            }
            bK = bKn;
        }
        // PV for this 32-wide j block
#pragma unroll
        for (int rt = 0; rt < 4; ++rt) {
            const bf16x8 aP = *(const bf16x8*)&PbW[(rt * 16 + l16) * 40 + quad * 8];
#pragma unroll
            for (int ct = 0; ct < 2; ++ct) {
                const bf16x8 bV = *(const bf16x8*)
                    &Vt[(ct * 16 + l16) * 264 + c2 * 32 + quad * 8];
                o_acc[rt][ct] = __builtin_amdgcn_mfma_f32_16x16x32_bf16(
                    aP, bV, o_acc[rt][ct], 0, 0, 0);
            }
        }
    }

    // softmax denominators: lane-local partial + reduce across quads
    float linv[4];
#pragma unroll
    for (int rt = 0; rt < 4; ++rt) {
        float v = lsum[rt];
        v += __shfl_xor(v, 16);
        v += __shfl_xor(v, 32);
        linv[rt] = 1.f / v;
    }

    __syncthreads();   // all waves done with Vt/Pb -> overlay Ol
#pragma unroll
    for (int rt = 0; rt < 4; ++rt) {
        const int i = wv * 64 + rt * 16 + quad * 4;
        float sc[4];
#pragma unroll
        for (int reg = 0; reg < 4; ++reg)
            sc[reg] = __shfl(linv[rt], quad * 4 + reg);
#pragma unroll
        for (int ct = 0; ct < 2; ++ct) {
            const int c = ct * 16 + l16;
#pragma unroll
            for (int reg = 0; reg < 4; ++reg)
                Ol[c * 257 + i + reg] = o_acc[rt][ct][reg] * sc[reg];
        }
    }
    __syncthreads();

    ushort_t* op = att + ((size_t)b * HW + (size_t)y * W + t) * C + head * HD;
#pragma unroll
    for (int g8 = 0; g8 < 4; ++g8) {
        bf16x8 o;
#pragma unroll
        for (int k = 0; k < 8; ++k)
            o[k] = (short)f2bfbits(Ol[(g8 * 8 + k) * 257 + t]);
        *(bf16x8*)(op + g8 * 8) = o;
    }
}

// ---------------------------------------------------------------------------
extern "C" void kernel_launch(void* const* d_in, const int* in_sizes, int n_in,
                              void* d_out, int out_size, void* d_ws, size_t ws_size,
                              hipStream_t stream)
{
    const float* x       = (const float*)d_in[0];
    const float* rpb     = (const float*)d_in[1];
    const float* w_qkv   = (const float*)d_in[2];
    const float* w_depth = (const float*)d_in[3];
    const float* w_pre   = (const float*)d_in[4];
    const float* w_out   = (const float*)d_in[5];
    const float* w_gate  = (const float*)d_in[6];
    float* out = (float*)d_out;

    // workspace layout (176.7 MB), aliased by lifetime:
    char* wsb = (char*)d_ws;
    ushort_t* wbf      = (ushort_t*)wsb;
    ushort_t* w_qkv_b  = wbf;
    ushort_t* w_gate_b = wbf + 110592;
    ushort_t* w_pre_b  = wbf + 147456;
    ushort_t* w_out_b  = wbf + 184320;
    ushort_t* gate_t   = (ushort_t*)(wsb + 524288u);
    ushort_t* buf_t    = (ushort_t*)(wsb + 25690112u);
    ushort_t* att_t    = (ushort_t*)(wsb + 25690112u);
    ushort_t* y_t      = (ushort_t*)(wsb + 50855936u);
    ushort_t* buf_qkv  = (ushort_t*)(wsb + 101187584u);
    ushort_t* x_t      = (ushort_t*)(wsb + 101187584u);

    dim3 blk(256);

    prep_w_kernel<<<dim3(216), blk, 0, stream>>>(w_qkv, w_gate, w_pre, w_out, wbf);
    transpose_x_kernel<<<dim3(NPX / 64), blk, 0, stream>>>(x, x_t);
    // gate_t = silu(x_t @ w_gate)             px-major bf16
    conv_mfma_kernel<1, 0, 3><<<dim3(384), blk, 0, stream>>>(
        x_t, w_gate_b, gate_t, nullptr, C);
    // t = x_t @ w_qkv (q-rows pre-scaled)     px-major bf16 [px][576]
    conv_mfma_kernel<0, 0, 9><<<dim3(1152), blk, 0, stream>>>(
        x_t, w_qkv_b, buf_t, nullptr, C3);
    // qkv = depthwise3x3(t)                   px-major bf16 [px][576]
    dwconv3x3_px_kernel<<<dim3(NPX / 128, 9), blk, 0, stream>>>(
        buf_t, w_depth, buf_qkv);
    // att_t = attention(qkv, rpb)             px-major bf16
    attention_mfma_kernel<<<dim3(H, HEADS, BATCH), blk, 0, stream>>>(
        buf_qkv, rpb, att_t);
    // y_t = (att_t @ w_pre) * gate_t          px-major bf16
    conv_mfma_kernel<2, 0, 3><<<dim3(384), blk, 0, stream>>>(
        att_t, w_pre_b, y_t, gate_t, C);
    // out = y_t @ w_out                       ch-major f32
    conv_mfma_kernel<0, 1, 3><<<dim3(384), blk, 0, stream>>>(
        y_t, w_out_b, out, nullptr, C);
}

// Round 2
// 309.185 us; speedup vs baseline: 1.1359x; 1.0614x over previous
//
#include <hip/hip_runtime.h>
#include <hip/hip_bf16.h>
#include <math.h>

#define BATCH 2
#define C 192
#define H 128
#define W 256
#define HEADS 6
#define HD 32
#define HW (H * W)      // 32768
#define C3 (3 * C)      // 576
#define NPX (BATCH * HW)  // 65536

typedef unsigned short ushort_t;
using bf16x8 = __attribute__((ext_vector_type(8))) short;
using f32x4  = __attribute__((ext_vector_type(4))) float;

static __device__ __forceinline__ float bfbits2f(ushort_t u) {
    return __uint_as_float(((unsigned)u) << 16);
}
static __device__ __forceinline__ ushort_t f2bfbits(float f) {
    __hip_bfloat16 h = __float2bfloat16(f);
    return *reinterpret_cast<ushort_t*>(&h);
}

// ---------------------------------------------------------------------------
// prep_w: fp32 -> bf16 weights; q-rows of w_qkv pre-scaled by 32^-0.5*log2(e)
// (softmax computed in base-2; exp2 saves the per-element ln2 multiply).
// Layout: w_qkv rows 0..575 | w_gate rows 576..767 | w_pre | w_out  (rows of
// 192 bf16) — qkv+gate contiguous so the fused GEMM reads one weight array.
// ---------------------------------------------------------------------------
__global__ __launch_bounds__(256) void prep_w_kernel(
    const float* __restrict__ wq, const float* __restrict__ wg,
    const float* __restrict__ wp, const float* __restrict__ wo,
    ushort_t* __restrict__ dst)
{
    const int i = blockIdx.x * 256 + threadIdx.x;   // float4 index, < 55296
    const float* src; int off, base;
    if (i < 27648)      { src = wq; off = i;         base = 0; }
    else if (i < 36864) { src = wg; off = i - 27648; base = 110592; }
    else if (i < 46080) { src = wp; off = i - 36864; base = 147456; }
    else                { src = wo; off = i - 46080; base = 184320; }
    float4 v = ((const float4*)src)[off];
    if (i < 9216) {   // w_qkv rows 0..191 (the q projection)
        const float sc = 0.25503488f;   // 32^-0.5 * log2(e)
        v.x *= sc; v.y *= sc; v.z *= sc; v.w *= sc;
    }
    ushort4 o;
    o.x = f2bfbits(v.x); o.y = f2bfbits(v.y);
    o.z = f2bfbits(v.z); o.w = f2bfbits(v.w);
    *(ushort4*)(dst + base + off * 4) = o;
}

// ---------------------------------------------------------------------------
// transpose_x: x [B][192][HW] f32 -> x_t [B*HW][192] bf16 (pixel-major).
// ---------------------------------------------------------------------------
__global__ __launch_bounds__(256) void transpose_x_kernel(
    const float* __restrict__ x, ushort_t* __restrict__ xt)
{
    __shared__ uint Xs[64 * 97];   // 24.8 KB
    const int p0 = blockIdx.x * 64;
    const int b  = p0 >> 15, hw0 = p0 & (HW - 1);
    const int t  = threadIdx.x;

    {
        const int px = t & 63, g = t >> 6;
        const float* xb = x + (size_t)b * C * HW + hw0 + px;
#pragma unroll
        for (int i = 0; i < 24; ++i) {
            const int cp = g + i * 4;   // channel pair 0..95
            const float v0 = xb[(size_t)(2 * cp) * HW];
            const float v1 = xb[(size_t)(2 * cp + 1) * HW];
            Xs[px * 97 + cp] = (uint)f2bfbits(v0) | ((uint)f2bfbits(v1) << 16);
        }
    }
    __syncthreads();
    {
        const int px = t >> 2, grp = t & 3;
        uint* dst = (uint*)(xt + (size_t)(p0 + px) * C) + grp * 24;
        const uint* s = &Xs[px * 97 + grp * 24];
#pragma unroll
        for (int i = 0; i < 6; ++i) {
            uint4 u;
            u.x = s[i * 4 + 0]; u.y = s[i * 4 + 1];
            u.z = s[i * 4 + 2]; u.w = s[i * 4 + 3];
            *(uint4*)(dst + i * 4) = u;
        }
    }
}

// ---------------------------------------------------------------------------
// MFMA conv1x1 GEMM v3. Block: 4 waves; tile M=64(ch) x N=256(px), K=192.
// v2 had wave tile 64x128 (acc[4][8] = 128 regs + 64 frag regs -> ~1 block/CU,
// OccupancyPercent 8.4%, everything latency-exposed). v3 halves the wave tile
// to 64x64: acc[4][4]=64 regs, frags 32 -> ~3 waves/SIMD (launch_bounds 256,3)
// while keeping the same MFMA:B-load ratio (4 MFMA per 16B gather).
// Grid: lin = xcd + 8*(m + MT*pin), pin 0..31 (NPX/256 = 256 px tiles =
// 8 xcd * 32), so all MT m-blocks of a px-tile share one XCD L2.
// MODE 0: none; 1: silu; 2: multiply by px-major gate; 3: fused qkv+gate
//   (MT=12: m 0..8 -> buf_t [px][576]; m 9..11 -> silu -> gate [px][192]).
// OUTKIND 0: px-major bf16; 1: ch-major f32 (final output).
// ---------------------------------------------------------------------------
template <int MODE, int OUTKIND, int MT>
__global__ __launch_bounds__(256, 3) void conv_mfma_kernel(
    const ushort_t* __restrict__ in_t, const ushort_t* __restrict__ w_bf,
    void* __restrict__ outp, ushort_t* __restrict__ gate, int ostride)
{
    const int lin = blockIdx.x;
    const int xcd = lin & 7;
    const int jj  = lin >> 3;
    const int pin = jj / MT;            // 0..31
    const int m   = jj - pin * MT;      // 0..MT-1
    const int m0  = m * 64;
    const int p0  = (xcd * 32 + pin) * 256;

    const int t  = threadIdx.x;
    const int wv = t >> 6, lane = t & 63, quad = lane >> 4, l16 = lane & 15;

    // ---- stage A (weights m0..m0+63 x 192) into LDS, padded to 200 ----
    __shared__ ushort_t As[64 * 200];   // 25.6 KB
    {
        const int row = t >> 2, cg = (t & 3) * 48;
        const ushort_t* src = w_bf + (size_t)(m0 + row) * C + cg;
        ushort_t* dst = &As[row * 200 + cg];
#pragma unroll
        for (int i = 0; i < 6; ++i)
            *(bf16x8*)(dst + i * 8) = *(const bf16x8*)(src + i * 8);
    }
    __syncthreads();

    f32x4 acc[4][4];
#pragma unroll
    for (int rt = 0; rt < 4; ++rt)
#pragma unroll
        for (int ct = 0; ct < 4; ++ct) acc[rt][ct] = f32x4{0.f, 0.f, 0.f, 0.f};

    const ushort_t* bp = in_t + (size_t)(p0 + wv * 64 + l16) * C + quad * 8;

    bf16x8 bF[4], bFn[4];
#pragma unroll
    for (int ct = 0; ct < 4; ++ct)
        bF[ct] = *(const bf16x8*)(bp + (size_t)(ct * 16) * C);

#pragma unroll
    for (int ks = 0; ks < 6; ++ks) {
        if (ks < 5) {
#pragma unroll
            for (int ct = 0; ct < 4; ++ct)
                bFn[ct] = *(const bf16x8*)(bp + (size_t)(ct * 16) * C +
                                           (ks + 1) * 32);
        }
        bf16x8 aF[4];
#pragma unroll
        for (int rt = 0; rt < 4; ++rt)
            aF[rt] = *(const bf16x8*)&As[(rt * 16 + l16) * 200 + quad * 8 + ks * 32];
#pragma unroll
        for (int rt = 0; rt < 4; ++rt)
#pragma unroll
            for (int ct = 0; ct < 4; ++ct)
                acc[rt][ct] = __builtin_amdgcn_mfma_f32_16x16x32_bf16(
                    aF[rt], bF[ct], acc[rt][ct], 0, 0, 0);
#pragma unroll
        for (int ct = 0; ct < 4; ++ct) bF[ct] = bFn[ct];
    }

    // ---- epilogue ----
    const bool isg = (MODE == 3) && (m >= 9);   // gate block of fused kernel
    if (MODE == 1 || isg) {
#pragma unroll
        for (int rt = 0; rt < 4; ++rt)
#pragma unroll
            for (int ct = 0; ct < 4; ++ct) {
                f32x4 v = acc[rt][ct];
#pragma unroll
                for (int r = 0; r < 4; ++r)
                    v[r] = v[r] / (1.f + __expf(-v[r]));
                acc[rt][ct] = v;
            }
    }

    if constexpr (OUTKIND == 0) {
        ushort_t* ob; int osr, chb;
        if constexpr (MODE == 3) {
            ob  = isg ? gate : (ushort_t*)outp;
            osr = isg ? C : C3;
            chb = isg ? m0 - C3 : m0;
        } else {
            ob = (ushort_t*)outp; osr = ostride; chb = m0;
        }
#pragma unroll
        for (int rt = 0; rt < 4; ++rt)
#pragma unroll
            for (int ct = 0; ct < 4; ++ct) {
                const int px = p0 + wv * 64 + ct * 16 + l16;
                const int ch = chb + rt * 16 + quad * 4;
                f32x4 v = acc[rt][ct];
                if (MODE == 2) {
                    const ushort4 g = *(const ushort4*)(gate + (size_t)px * C + ch);
                    v[0] *= bfbits2f(g.x); v[1] *= bfbits2f(g.y);
                    v[2] *= bfbits2f(g.z); v[3] *= bfbits2f(g.w);
                }
                ushort4 o;
                o.x = f2bfbits(v[0]); o.y = f2bfbits(v[1]);
                o.z = f2bfbits(v[2]); o.w = f2bfbits(v[3]);
                *(ushort4*)(ob + (size_t)px * osr + ch) = o;
            }
    } else {
        // channel-major f32 [B][192][HW] (final output)
        const int bb = p0 >> 15;
        const int hwb = (p0 & (HW - 1)) + wv * 64;
        float* ob = (float*)outp + ((size_t)bb * C + m0) * HW + hwb;
#pragma unroll
        for (int rt = 0; rt < 4; ++rt)
#pragma unroll
            for (int ct = 0; ct < 4; ++ct) {
                const f32x4 v = acc[rt][ct];
#pragma unroll
                for (int r = 0; r < 4; ++r)
                    ob[(size_t)(rt * 16 + quad * 4 + r) * HW + ct * 16 + l16] = v[r];
            }
    }
}

// ---------------------------------------------------------------------------
// depthwise 3x3, pixel-major (unchanged).
// ---------------------------------------------------------------------------
__global__ __launch_bounds__(256) void dwconv3x3_px_kernel(
    const ushort_t* __restrict__ tin, const float* __restrict__ wd,
    ushort_t* __restrict__ out)
{
    __shared__ float wloc[576];
    const int cb  = blockIdx.y;
    const int tid = threadIdx.x;
    if (tid < 144)
        *(float4*)&wloc[tid * 4] = *(const float4*)(wd + cb * 576 + tid * 4);
    __syncthreads();

    const int chloc = (tid & 7) * 8;
    const int px = blockIdx.x * 128 + (tid >> 3) * 4;
    const int x0 = px & (W - 1);
    const int y  = (px >> 8) & (H - 1);

    const ushort_t* tb = tin + (size_t)px * C3 + cb * 64 + chloc;

    float acc[4][8];
#pragma unroll
    for (int i = 0; i < 4; ++i)
#pragma unroll
        for (int k = 0; k < 8; ++k) acc[i][k] = 0.f;

#pragma unroll
    for (int dy = -1; dy <= 1; ++dy) {
        const int yy = y + dy;
        if (yy < 0 || yy >= H) continue;
        const ushort_t* rp = tb + (ptrdiff_t)dy * W * C3;

        float f[6][8];
#pragma unroll
        for (int d = 0; d < 6; ++d) {
            const int xx = x0 + d - 1;
            if (xx < 0 || xx >= W) {
#pragma unroll
                for (int k = 0; k < 8; ++k) f[d][k] = 0.f;
            } else {
                const bf16x8 v = *(const bf16x8*)(rp + (ptrdiff_t)(d - 1) * C3);
#pragma unroll
                for (int k = 0; k < 8; ++k) f[d][k] = bfbits2f((ushort_t)v[k]);
            }
        }
#pragma unroll
        for (int k = 0; k < 8; ++k) {
            const float* wk = &wloc[(chloc + k) * 9 + (dy + 1) * 3];
            const float w0 = wk[0], w1 = wk[1], w2 = wk[2];
#pragma unroll
            for (int i = 0; i < 4; ++i)
                acc[i][k] += f[i][k] * w0 + f[i + 1][k] * w1 + f[i + 2][k] * w2;
        }
    }

    ushort_t* ob = out + (size_t)px * C3 + cb * 64 + chloc;
#pragma unroll
    for (int i = 0; i < 4; ++i) {
        bf16x8 o;
#pragma unroll
        for (int k = 0; k < 8; ++k) o[k] = (short)f2bfbits(acc[i][k]);
        *(bf16x8*)(ob + (size_t)i * C3) = o;
    }
}

// ---------------------------------------------------------------------------
// MFMA attention v2 (unchanged from last round): swapped QK^T, base-2
// softmax, no Q/K LDS staging, 39424 B LDS -> 4 blocks/CU.
// ---------------------------------------------------------------------------
__global__ __launch_bounds__(256, 4) void attention_mfma_kernel(
    const ushort_t* __restrict__ qkv, const float* __restrict__ rpb,
    ushort_t* __restrict__ att)
{
    const int y    = blockIdx.x;
    const int head = blockIdx.y;
    const int b    = blockIdx.z;
    const int t    = threadIdx.x;
    const int wv   = t >> 6;
    const int lane = t & 63;
    const int quad = lane >> 4;
    const int l16  = lane & 15;

    __shared__ __align__(16) char smem[39424];
    ushort_t* Vt = (ushort_t*)smem;               // [32][264]  = 16896 B
    ushort_t* Pb = (ushort_t*)(smem + 16896);     // [4][64][40]= 20480 B
    ushort_t* rb = (ushort_t*)(smem + 37376);     // [2][512]   =  2048 B
    float*    Ol = (float*)smem;                  // [32][257] epilogue overlay

    const size_t rowbase = ((size_t)b * HW + (size_t)y * W) * C3;
    const ushort_t* qbase = qkv + rowbase + head * HD + quad * 8;
    const ushort_t* kbase = qbase + C;

    // ---- stage V transposed into LDS; build base-2 rpb table (2 copies) ----
    {
        const ushort_t* rowp = qkv + rowbase + (size_t)t * C3 + head * HD;
        bf16x8 vfr[4];
#pragma unroll
        for (int g = 0; g < 4; ++g)
            vfr[g] = *(const bf16x8*)(rowp + 2 * C + g * 8);
#pragma unroll
        for (int g = 0; g < 4; ++g)
#pragma unroll
            for (int k = 0; k < 8; ++k)
                Vt[(g * 8 + k) * 264 + t] = (ushort_t)vfr[g][k];
    }
    {
        const float LOG2E = 1.4426950408889634f;
#pragma unroll
        for (int s2 = 0; s2 < 2; ++s2)
#pragma unroll
            for (int pp = 0; pp < 2; ++pp) {
                const int k = pp * 256 + t;
                const int src = k + s2;
                rb[s2 * 512 + k] =
                    f2bfbits(src <= 510 ? rpb[src * HEADS + head] * LOG2E : 0.f);
            }
    }

    // Q fragments (B-operand layout) direct from global; first K fragment.
    bf16x8 aQ[4];
#pragma unroll
    for (int rt = 0; rt < 4; ++rt)
        aQ[rt] = *(const bf16x8*)(qbase + (size_t)(wv * 64 + rt * 16 + l16) * C3);
    bf16x8 bK = *(const bf16x8*)(kbase + (size_t)l16 * C3);

    __syncthreads();

    ushort_t* PbW = Pb + wv * 2560;
    float lsum[4] = {0.f, 0.f, 0.f, 0.f};
    f32x4 o_acc[4][2];
#pragma unroll
    for (int rt = 0; rt < 4; ++rt)
#pragma unroll
        for (int ct = 0; ct < 2; ++ct)
            o_acc[rt][ct] = f32x4{0.f, 0.f, 0.f, 0.f};

    const int ibase = wv * 64 + l16 + 255 - quad * 4;

    for (int c2 = 0; c2 < 8; ++c2) {
#pragma unroll
        for (int half = 0; half < 2; ++half) {
            const int n  = c2 * 2 + half;
            const int nn = (n < 15) ? n + 1 : 15;
            const bf16x8 bKn =
                *(const bf16x8*)(kbase + (size_t)(nn * 16 + l16) * C3);
#pragma unroll
            for (int rt = 0; rt < 4; ++rt) {
                // bias^T: idx = i - j + 255 = (ibase + rt*16 - n*16) - reg
                const int a  = ibase + rt * 16 - n * 16 - 3;  // 0..507
                const int s2 = a & 1;
                const uint* tp = (const uint*)(rb + s2 * 512 + (a - s2));
                const uint u0 = tp[0], u1 = tp[1];  // rpb2[a..a+3]
                f32x4 s;
                s[0] = __uint_as_float(u1 & 0xffff0000u);
                s[1] = __uint_as_float(u1 << 16);
                s[2] = __uint_as_float(u0 & 0xffff0000u);
                s[3] = __uint_as_float(u0 << 16);
                s = __builtin_amdgcn_mfma_f32_16x16x32_bf16(bK, aQ[rt], s, 0, 0, 0);
                const float p0 = __builtin_amdgcn_exp2f(s[0]);
                const float p1 = __builtin_amdgcn_exp2f(s[1]);
                const float p2 = __builtin_amdgcn_exp2f(s[2]);
                const float p3 = __builtin_amdgcn_exp2f(s[3]);
                lsum[rt] += (p0 + p1) + (p2 + p3);
                uint2 dd;
                dd.x = (uint)f2bfbits(p0) | ((uint)f2bfbits(p1) << 16);
                dd.y = (uint)f2bfbits(p2) | ((uint)f2bfbits(p3) << 16);
                *(uint2*)&PbW[(rt * 16 + l16) * 40 + half * 16 + quad * 4] = dd;
            }
            bK = bKn;
        }
        // PV for this 32-wide j block
#pragma unroll
        for (int rt = 0; rt < 4; ++rt) {
            const bf16x8 aP = *(const bf16x8*)&PbW[(rt * 16 + l16) * 40 + quad * 8];
#pragma unroll
            for (int ct = 0; ct < 2; ++ct) {
                const bf16x8 bV = *(const bf16x8*)
                    &Vt[(ct * 16 + l16) * 264 + c2 * 32 + quad * 8];
                o_acc[rt][ct] = __builtin_amdgcn_mfma_f32_16x16x32_bf16(
                    aP, bV, o_acc[rt][ct], 0, 0, 0);
            }
        }
    }

    // softmax denominators: lane-local partial + reduce across quads
    float linv[4];
#pragma unroll
    for (int rt = 0; rt < 4; ++rt) {
        float v = lsum[rt];
        v += __shfl_xor(v, 16);
        v += __shfl_xor(v, 32);
        linv[rt] = 1.f / v;
    }

    __syncthreads();   // all waves done with Vt/Pb -> overlay Ol
#pragma unroll
    for (int rt = 0; rt < 4; ++rt) {
        const int i = wv * 64 + rt * 16 + quad * 4;
        float sc[4];
#pragma unroll
        for (int reg = 0; reg < 4; ++reg)
            sc[reg] = __shfl(linv[rt], quad * 4 + reg);
#pragma unroll
        for (int ct = 0; ct < 2; ++ct) {
            const int c = ct * 16 + l16;
#pragma unroll
            for (int reg = 0; reg < 4; ++reg)
                Ol[c * 257 + i + reg] = o_acc[rt][ct][reg] * sc[reg];
        }
    }
    __syncthreads();

    ushort_t* op = att + ((size_t)b * HW + (size_t)y * W + t) * C + head * HD;
#pragma unroll
    for (int g8 = 0; g8 < 4; ++g8) {
        bf16x8 o;
#pragma unroll
        for (int k = 0; k < 8; ++k)
            o[k] = (short)f2bfbits(Ol[(g8 * 8 + k) * 257 + t]);
        *(bf16x8*)(op + g8 * 8) = o;
    }
}

// ---------------------------------------------------------------------------
extern "C" void kernel_launch(void* const* d_in, const int* in_sizes, int n_in,
                              void* d_out, int out_size, void* d_ws, size_t ws_size,
                              hipStream_t stream)
{
    const float* x       = (const float*)d_in[0];
    const float* rpb     = (const float*)d_in[1];
    const float* w_qkv   = (const float*)d_in[2];
    const float* w_depth = (const float*)d_in[3];
    const float* w_pre   = (const float*)d_in[4];
    const float* w_out   = (const float*)d_in[5];
    const float* w_gate  = (const float*)d_in[6];
    float* out = (float*)d_out;

    // workspace layout (176.7 MB), aliased by lifetime:
    char* wsb = (char*)d_ws;
    ushort_t* wbf      = (ushort_t*)wsb;           // qkv|gate|pre|out rows
    ushort_t* w_pre_b  = wbf + 147456;
    ushort_t* w_out_b  = wbf + 184320;
    ushort_t* gate_t   = (ushort_t*)(wsb + 524288u);
    ushort_t* buf_t    = (ushort_t*)(wsb + 25690112u);
    ushort_t* att_t    = (ushort_t*)(wsb + 25690112u);
    ushort_t* y_t      = (ushort_t*)(wsb + 50855936u);
    ushort_t* buf_qkv  = (ushort_t*)(wsb + 101187584u);
    ushort_t* x_t      = (ushort_t*)(wsb + 101187584u);

    dim3 blk(256);

    prep_w_kernel<<<dim3(216), blk, 0, stream>>>(w_qkv, w_gate, w_pre, w_out, wbf);
    transpose_x_kernel<<<dim3(NPX / 64), blk, 0, stream>>>(x, x_t);
    // fused: buf_t = x_t @ w_qkv (q pre-scaled), gate_t = silu(x_t @ w_gate)
    conv_mfma_kernel<3, 0, 12><<<dim3(3072), blk, 0, stream>>>(
        x_t, wbf, buf_t, gate_t, C3);
    // qkv = depthwise3x3(t)                   px-major bf16 [px][576]
    dwconv3x3_px_kernel<<<dim3(NPX / 128, 9), blk, 0, stream>>>(
        buf_t, w_depth, buf_qkv);
    // att_t = attention(qkv, rpb)             px-major bf16
    attention_mfma_kernel<<<dim3(H, HEADS, BATCH), blk, 0, stream>>>(
        buf_qkv, rpb, att_t);
    // y_t = (att_t @ w_pre) * gate_t          px-major bf16
    conv_mfma_kernel<2, 0, 3><<<dim3(768), blk, 0, stream>>>(
        att_t, w_pre_b, y_t, gate_t, C);
    // out = y_t @ w_out                       ch-major f32
    conv_mfma_kernel<0, 1, 3><<<dim3(768), blk, 0, stream>>>(
        y_t, w_out_b, out, nullptr, C);
}

// Round 3
// 305.537 us; speedup vs baseline: 1.1495x; 1.0119x over previous
//
#include <hip/hip_runtime.h>
#include <hip/hip_bf16.h>
#include <math.h>

#define BATCH 2
#define C 192
#define H 128
#define W 256
#define HEADS 6
#define HD 32
#define HW (H * W)      // 32768
#define C3 (3 * C)      // 576
#define NPX (BATCH * HW)  // 65536

typedef unsigned short ushort_t;
using bf16x8 = __attribute__((ext_vector_type(8))) short;
using f32x4  = __attribute__((ext_vector_type(4))) float;

static __device__ __forceinline__ float bfbits2f(ushort_t u) {
    return __uint_as_float(((unsigned)u) << 16);
}
static __device__ __forceinline__ ushort_t f2bfbits(float f) {
    __hip_bfloat16 h = __float2bfloat16(f);
    return *reinterpret_cast<ushort_t*>(&h);
}

// ---------------------------------------------------------------------------
// prep_w: fp32 -> bf16 weights; q-rows of w_qkv pre-scaled by 32^-0.5*log2(e)
// (softmax computed in base-2; exp2 saves the per-element ln2 multiply).
// Layout: w_qkv rows 0..575 | w_gate rows 576..767 | w_pre | w_out  (rows of
// 192 bf16) — qkv+gate contiguous so the fused GEMM reads one weight array.
// ---------------------------------------------------------------------------
__global__ __launch_bounds__(256) void prep_w_kernel(
    const float* __restrict__ wq, const float* __restrict__ wg,
    const float* __restrict__ wp, const float* __restrict__ wo,
    ushort_t* __restrict__ dst)
{
    const int i = blockIdx.x * 256 + threadIdx.x;   // float4 index, < 55296
    const float* src; int off, base;
    if (i < 27648)      { src = wq; off = i;         base = 0; }
    else if (i < 36864) { src = wg; off = i - 27648; base = 110592; }
    else if (i < 46080) { src = wp; off = i - 36864; base = 147456; }
    else                { src = wo; off = i - 46080; base = 184320; }
    float4 v = ((const float4*)src)[off];
    if (i < 9216) {   // w_qkv rows 0..191 (the q projection)
        const float sc = 0.25503488f;   // 32^-0.5 * log2(e)
        v.x *= sc; v.y *= sc; v.z *= sc; v.w *= sc;
    }
    ushort4 o;
    o.x = f2bfbits(v.x); o.y = f2bfbits(v.y);
    o.z = f2bfbits(v.z); o.w = f2bfbits(v.w);
    *(ushort4*)(dst + base + off * 4) = o;
}

// ---------------------------------------------------------------------------
// transpose_x: x [B][192][HW] f32 -> x_t [B*HW][192] bf16 (pixel-major).
// ---------------------------------------------------------------------------
__global__ __launch_bounds__(256) void transpose_x_kernel(
    const float* __restrict__ x, ushort_t* __restrict__ xt)
{
    __shared__ uint Xs[64 * 97];   // 24.8 KB
    const int p0 = blockIdx.x * 64;
    const int b  = p0 >> 15, hw0 = p0 & (HW - 1);
    const int t  = threadIdx.x;

    {
        const int px = t & 63, g = t >> 6;
        const float* xb = x + (size_t)b * C * HW + hw0 + px;
#pragma unroll
        for (int i = 0; i < 24; ++i) {
            const int cp = g + i * 4;   // channel pair 0..95
            const float v0 = xb[(size_t)(2 * cp) * HW];
            const float v1 = xb[(size_t)(2 * cp + 1) * HW];
            Xs[px * 97 + cp] = (uint)f2bfbits(v0) | ((uint)f2bfbits(v1) << 16);
        }
    }
    __syncthreads();
    {
        const int px = t >> 2, grp = t & 3;
        uint* dst = (uint*)(xt + (size_t)(p0 + px) * C) + grp * 24;
        const uint* s = &Xs[px * 97 + grp * 24];
#pragma unroll
        for (int i = 0; i < 6; ++i) {
            uint4 u;
            u.x = s[i * 4 + 0]; u.y = s[i * 4 + 1];
            u.z = s[i * 4 + 2]; u.w = s[i * 4 + 3];
            *(uint4*)(dst + i * 4) = u;
        }
    }
}

// ---------------------------------------------------------------------------
// MFMA conv1x1 GEMM v4. Block: 4 waves; tile M=64(ch) x N=256(px), K=192.
// v3 lesson: occupancy 8->25% left throughput IDENTICAL -> not a TLP problem.
// The wall was per-K-step exposed B-gather latency (compiler collapsed the
// 1-deep prefetch; VGPR_Count=72 proved it). v4 pays latency ONCE per wave:
// all 24 B fragments (full K panel, 96 VGPRs) are issued before the A-stage;
// the barrier drains them while A stages; the MFMA loop then runs purely from
// registers+LDS. launch_bounds(256,2): ~200 unified regs, 2 waves/SIMD —
// ILP replaces TLP.
// Grid: lin = xcd + 8*(m + MT*pin), pin 0..31; px-tile shares one XCD L2.
// MODE 0: none; 1: silu; 2: multiply by px-major gate; 3: fused qkv+gate
//   (MT=12: m 0..8 -> buf_t [px][576]; m 9..11 -> silu -> gate [px][192]).
// OUTKIND 0: px-major bf16; 1: ch-major f32 (final output).
// ---------------------------------------------------------------------------
template <int MODE, int OUTKIND, int MT>
__global__ __launch_bounds__(256, 2) void conv_mfma_kernel(
    const ushort_t* __restrict__ in_t, const ushort_t* __restrict__ w_bf,
    void* __restrict__ outp, ushort_t* __restrict__ gate, int ostride)
{
    const int lin = blockIdx.x;
    const int xcd = lin & 7;
    const int jj  = lin >> 3;
    const int pin = jj / MT;            // 0..31
    const int m   = jj - pin * MT;      // 0..MT-1
    const int m0  = m * 64;
    const int p0  = (xcd * 32 + pin) * 256;

    const int t  = threadIdx.x;
    const int wv = t >> 6, lane = t & 63, quad = lane >> 4, l16 = lane & 15;

    // ---- issue the wave's FULL B panel first (24x 16B gathers in flight) ---
    const ushort_t* bp = in_t + (size_t)(p0 + wv * 64 + l16) * C + quad * 8;
    bf16x8 bF[6][4];
#pragma unroll
    for (int ks = 0; ks < 6; ++ks)
#pragma unroll
        for (int ct = 0; ct < 4; ++ct)
            bF[ks][ct] = *(const bf16x8*)(bp + (size_t)(ct * 16) * C + ks * 32);

    // ---- stage A (weights m0..m0+63 x 192) into LDS, padded to 200 ----
    __shared__ ushort_t As[64 * 200];   // 25.6 KB
    {
        const int row = t >> 2, cg = (t & 3) * 48;
        const ushort_t* src = w_bf + (size_t)(m0 + row) * C + cg;
        ushort_t* dst = &As[row * 200 + cg];
#pragma unroll
        for (int i = 0; i < 6; ++i)
            *(bf16x8*)(dst + i * 8) = *(const bf16x8*)(src + i * 8);
    }
    __syncthreads();

    f32x4 acc[4][4];
#pragma unroll
    for (int rt = 0; rt < 4; ++rt)
#pragma unroll
        for (int ct = 0; ct < 4; ++ct) acc[rt][ct] = f32x4{0.f, 0.f, 0.f, 0.f};

    // ---- pure register/LDS MFMA loop: no global latency inside ----
#pragma unroll
    for (int ks = 0; ks < 6; ++ks) {
        bf16x8 aF[4];
#pragma unroll
        for (int rt = 0; rt < 4; ++rt)
            aF[rt] = *(const bf16x8*)&As[(rt * 16 + l16) * 200 + quad * 8 + ks * 32];
#pragma unroll
        for (int rt = 0; rt < 4; ++rt)
#pragma unroll
            for (int ct = 0; ct < 4; ++ct)
                acc[rt][ct] = __builtin_amdgcn_mfma_f32_16x16x32_bf16(
                    aF[rt], bF[ks][ct], acc[rt][ct], 0, 0, 0);
    }

    // ---- epilogue ----
    const bool isg = (MODE == 3) && (m >= 9);   // gate block of fused kernel
    if (MODE == 1 || isg) {
#pragma unroll
        for (int rt = 0; rt < 4; ++rt)
#pragma unroll
            for (int ct = 0; ct < 4; ++ct) {
                f32x4 v = acc[rt][ct];
#pragma unroll
                for (int r = 0; r < 4; ++r)
                    v[r] = v[r] / (1.f + __expf(-v[r]));
                acc[rt][ct] = v;
            }
    }

    if constexpr (OUTKIND == 0) {
        ushort_t* ob; int osr, chb;
        if constexpr (MODE == 3) {
            ob  = isg ? gate : (ushort_t*)outp;
            osr = isg ? C : C3;
            chb = isg ? m0 - C3 : m0;
        } else {
            ob = (ushort_t*)outp; osr = ostride; chb = m0;
        }
#pragma unroll
        for (int rt = 0; rt < 4; ++rt)
#pragma unroll
            for (int ct = 0; ct < 4; ++ct) {
                const int px = p0 + wv * 64 + ct * 16 + l16;
                const int ch = chb + rt * 16 + quad * 4;
                f32x4 v = acc[rt][ct];
                if (MODE == 2) {
                    const ushort4 g = *(const ushort4*)(gate + (size_t)px * C + ch);
                    v[0] *= bfbits2f(g.x); v[1] *= bfbits2f(g.y);
                    v[2] *= bfbits2f(g.z); v[3] *= bfbits2f(g.w);
                }
                ushort4 o;
                o.x = f2bfbits(v[0]); o.y = f2bfbits(v[1]);
                o.z = f2bfbits(v[2]); o.w = f2bfbits(v[3]);
                *(ushort4*)(ob + (size_t)px * osr + ch) = o;
            }
    } else {
        // channel-major f32 [B][192][HW] (final output)
        const int bb = p0 >> 15;
        const int hwb = (p0 & (HW - 1)) + wv * 64;
        float* ob = (float*)outp + ((size_t)bb * C + m0) * HW + hwb;
#pragma unroll
        for (int rt = 0; rt < 4; ++rt)
#pragma unroll
            for (int ct = 0; ct < 4; ++ct) {
                const f32x4 v = acc[rt][ct];
#pragma unroll
                for (int r = 0; r < 4; ++r)
                    ob[(size_t)(rt * 16 + quad * 4 + r) * HW + ct * 16 + l16] = v[r];
            }
    }
}

// ---------------------------------------------------------------------------
// depthwise 3x3, pixel-major (unchanged).
// ---------------------------------------------------------------------------
__global__ __launch_bounds__(256) void dwconv3x3_px_kernel(
    const ushort_t* __restrict__ tin, const float* __restrict__ wd,
    ushort_t* __restrict__ out)
{
    __shared__ float wloc[576];
    const int cb  = blockIdx.y;
    const int tid = threadIdx.x;
    if (tid < 144)
        *(float4*)&wloc[tid * 4] = *(const float4*)(wd + cb * 576 + tid * 4);
    __syncthreads();

    const int chloc = (tid & 7) * 8;
    const int px = blockIdx.x * 128 + (tid >> 3) * 4;
    const int x0 = px & (W - 1);
    const int y  = (px >> 8) & (H - 1);

    const ushort_t* tb = tin + (size_t)px * C3 + cb * 64 + chloc;

    float acc[4][8];
#pragma unroll
    for (int i = 0; i < 4; ++i)
#pragma unroll
        for (int k = 0; k < 8; ++k) acc[i][k] = 0.f;

#pragma unroll
    for (int dy = -1; dy <= 1; ++dy) {
        const int yy = y + dy;
        if (yy < 0 || yy >= H) continue;
        const ushort_t* rp = tb + (ptrdiff_t)dy * W * C3;

        float f[6][8];
#pragma unroll
        for (int d = 0; d < 6; ++d) {
            const int xx = x0 + d - 1;
            if (xx < 0 || xx >= W) {
#pragma unroll
                for (int k = 0; k < 8; ++k) f[d][k] = 0.f;
            } else {
                const bf16x8 v = *(const bf16x8*)(rp + (ptrdiff_t)(d - 1) * C3);
#pragma unroll
                for (int k = 0; k < 8; ++k) f[d][k] = bfbits2f((ushort_t)v[k]);
            }
        }
#pragma unroll
        for (int k = 0; k < 8; ++k) {
            const float* wk = &wloc[(chloc + k) * 9 + (dy + 1) * 3];
            const float w0 = wk[0], w1 = wk[1], w2 = wk[2];
#pragma unroll
            for (int i = 0; i < 4; ++i)
                acc[i][k] += f[i][k] * w0 + f[i + 1][k] * w1 + f[i + 2][k] * w2;
        }
    }

    ushort_t* ob = out + (size_t)px * C3 + cb * 64 + chloc;
#pragma unroll
    for (int i = 0; i < 4; ++i) {
        bf16x8 o;
#pragma unroll
        for (int k = 0; k < 8; ++k) o[k] = (short)f2bfbits(acc[i][k]);
        *(bf16x8*)(ob + (size_t)i * C3) = o;
    }
}

// ---------------------------------------------------------------------------
// MFMA attention v2 (unchanged): swapped QK^T, base-2 softmax, no Q/K LDS
// staging, 39424 B LDS -> 4 blocks/CU.
// ---------------------------------------------------------------------------
__global__ __launch_bounds__(256, 4) void attention_mfma_kernel(
    const ushort_t* __restrict__ qkv, const float* __restrict__ rpb,
    ushort_t* __restrict__ att)
{
    const int y    = blockIdx.x;
    const int head = blockIdx.y;
    const int b    = blockIdx.z;
    const int t    = threadIdx.x;
    const int wv   = t >> 6;
    const int lane = t & 63;
    const int quad = lane >> 4;
    const int l16  = lane & 15;

    __shared__ __align__(16) char smem[39424];
    ushort_t* Vt = (ushort_t*)smem;               // [32][264]  = 16896 B
    ushort_t* Pb = (ushort_t*)(smem + 16896);     // [4][64][40]= 20480 B
    ushort_t* rb = (ushort_t*)(smem + 37376);     // [2][512]   =  2048 B
    float*    Ol = (float*)smem;                  // [32][257] epilogue overlay

    const size_t rowbase = ((size_t)b * HW + (size_t)y * W) * C3;
    const ushort_t* qbase = qkv + rowbase + head * HD + quad * 8;
    const ushort_t* kbase = qbase + C;

    // ---- stage V transposed into LDS; build base-2 rpb table (2 copies) ----
    {
        const ushort_t* rowp = qkv + rowbase + (size_t)t * C3 + head * HD;
        bf16x8 vfr[4];
#pragma unroll
        for (int g = 0; g < 4; ++g)
            vfr[g] = *(const bf16x8*)(rowp + 2 * C + g * 8);
#pragma unroll
        for (int g = 0; g < 4; ++g)
#pragma unroll
            for (int k = 0; k < 8; ++k)
                Vt[(g * 8 + k) * 264 + t] = (ushort_t)vfr[g][k];
    }
    {
        const float LOG2E = 1.4426950408889634f;
#pragma unroll
        for (int s2 = 0; s2 < 2; ++s2)
#pragma unroll
            for (int pp = 0; pp < 2; ++pp) {
                const int k = pp * 256 + t;
                const int src = k + s2;
                rb[s2 * 512 + k] =
                    f2bfbits(src <= 510 ? rpb[src * HEADS + head] * LOG2E : 0.f);
            }
    }

    // Q fragments (B-operand layout) direct from global; first K fragment.
    bf16x8 aQ[4];
#pragma unroll
    for (int rt = 0; rt < 4; ++rt)
        aQ[rt] = *(const bf16x8*)(qbase + (size_t)(wv * 64 + rt * 16 + l16) * C3);
    bf16x8 bK = *(const bf16x8*)(kbase + (size_t)l16 * C3);

    __syncthreads();

    ushort_t* PbW = Pb + wv * 2560;
    float lsum[4] = {0.f, 0.f, 0.f, 0.f};
    f32x4 o_acc[4][2];
#pragma unroll
    for (int rt = 0; rt < 4; ++rt)
#pragma unroll
        for (int ct = 0; ct < 2; ++ct)
            o_acc[rt][ct] = f32x4{0.f, 0.f, 0.f, 0.f};

    const int ibase = wv * 64 + l16 + 255 - quad * 4;

    for (int c2 = 0; c2 < 8; ++c2) {
#pragma unroll
        for (int half = 0; half < 2; ++half) {
            const int n  = c2 * 2 + half;
            const int nn = (n < 15) ? n + 1 : 15;
            const bf16x8 bKn =
                *(const bf16x8*)(kbase + (size_t)(nn * 16 + l16) * C3);
#pragma unroll
            for (int rt = 0; rt < 4; ++rt) {
                // bias^T: idx = i - j + 255 = (ibase + rt*16 - n*16) - reg
                const int a  = ibase + rt * 16 - n * 16 - 3;  // 0..507
                const int s2 = a & 1;
                const uint* tp = (const uint*)(rb + s2 * 512 + (a - s2));
                const uint u0 = tp[0], u1 = tp[1];  // rpb2[a..a+3]
                f32x4 s;
                s[0] = __uint_as_float(u1 & 0xffff0000u);
                s[1] = __uint_as_float(u1 << 16);
                s[2] = __uint_as_float(u0 & 0xffff0000u);
                s[3] = __uint_as_float(u0 << 16);
                s = __builtin_amdgcn_mfma_f32_16x16x32_bf16(bK, aQ[rt], s, 0, 0, 0);
                const float p0 = __builtin_amdgcn_exp2f(s[0]);
                const float p1 = __builtin_amdgcn_exp2f(s[1]);
                const float p2 = __builtin_amdgcn_exp2f(s[2]);
                const float p3 = __builtin_amdgcn_exp2f(s[3]);
                lsum[rt] += (p0 + p1) + (p2 + p3);
                uint2 dd;
                dd.x = (uint)f2bfbits(p0) | ((uint)f2bfbits(p1) << 16);
                dd.y = (uint)f2bfbits(p2) | ((uint)f2bfbits(p3) << 16);
                *(uint2*)&PbW[(rt * 16 + l16) * 40 + half * 16 + quad * 4] = dd;
            }
            bK = bKn;
        }
        // PV for this 32-wide j block
#pragma unroll
        for (int rt = 0; rt < 4; ++rt) {
            const bf16x8 aP = *(const bf16x8*)&PbW[(rt * 16 + l16) * 40 + quad * 8];
#pragma unroll
            for (int ct = 0; ct < 2; ++ct) {
                const bf16x8 bV = *(const bf16x8*)
                    &Vt[(ct * 16 + l16) * 264 + c2 * 32 + quad * 8];
                o_acc[rt][ct] = __builtin_amdgcn_mfma_f32_16x16x32_bf16(
                    aP, bV, o_acc[rt][ct], 0, 0, 0);
            }
        }
    }

    // softmax denominators: lane-local partial + reduce across quads
    float linv[4];
#pragma unroll
    for (int rt = 0; rt < 4; ++rt) {
        float v = lsum[rt];
        v += __shfl_xor(v, 16);
        v += __shfl_xor(v, 32);
        linv[rt] = 1.f / v;
    }

    __syncthreads();   // all waves done with Vt/Pb -> overlay Ol
#pragma unroll
    for (int rt = 0; rt < 4; ++rt) {
        const int i = wv * 64 + rt * 16 + quad * 4;
        float sc[4];
#pragma unroll
        for (int reg = 0; reg < 4; ++reg)
            sc[reg] = __shfl(linv[rt], quad * 4 + reg);
#pragma unroll
        for (int ct = 0; ct < 2; ++ct) {
            const int c = ct * 16 + l16;
#pragma unroll
            for (int reg = 0; reg < 4; ++reg)
                Ol[c * 257 + i + reg] = o_acc[rt][ct][reg] * sc[reg];
        }
    }
    __syncthreads();

    ushort_t* op = att + ((size_t)b * HW + (size_t)y * W + t) * C + head * HD;
#pragma unroll
    for (int g8 = 0; g8 < 4; ++g8) {
        bf16x8 o;
#pragma unroll
        for (int k = 0; k < 8; ++k)
            o[k] = (short)f2bfbits(Ol[(g8 * 8 + k) * 257 + t]);
        *(bf16x8*)(op + g8 * 8) = o;
    }
}

// ---------------------------------------------------------------------------
extern "C" void kernel_launch(void* const* d_in, const int* in_sizes, int n_in,
                              void* d_out, int out_size, void* d_ws, size_t ws_size,
                              hipStream_t stream)
{
    const float* x       = (const float*)d_in[0];
    const float* rpb     = (const float*)d_in[1];
    const float* w_qkv   = (const float*)d_in[2];
    const float* w_depth = (const float*)d_in[3];
    const float* w_pre   = (const float*)d_in[4];
    const float* w_out   = (const float*)d_in[5];
    const float* w_gate  = (const float*)d_in[6];
    float* out = (float*)d_out;

    // workspace layout (176.7 MB), aliased by lifetime:
    char* wsb = (char*)d_ws;
    ushort_t* wbf      = (ushort_t*)wsb;           // qkv|gate|pre|out rows
    ushort_t* w_pre_b  = wbf + 147456;
    ushort_t* w_out_b  = wbf + 184320;
    ushort_t* gate_t   = (ushort_t*)(wsb + 524288u);
    ushort_t* buf_t    = (ushort_t*)(wsb + 25690112u);
    ushort_t* att_t    = (ushort_t*)(wsb + 25690112u);
    ushort_t* y_t      = (ushort_t*)(wsb + 50855936u);
    ushort_t* buf_qkv  = (ushort_t*)(wsb + 101187584u);
    ushort_t* x_t      = (ushort_t*)(wsb + 101187584u);

    dim3 blk(256);

    prep_w_kernel<<<dim3(216), blk, 0, stream>>>(w_qkv, w_gate, w_pre, w_out, wbf);
    transpose_x_kernel<<<dim3(NPX / 64), blk, 0, stream>>>(x, x_t);
    // fused: buf_t = x_t @ w_qkv (q pre-scaled), gate_t = silu(x_t @ w_gate)
    conv_mfma_kernel<3, 0, 12><<<dim3(3072), blk, 0, stream>>>(
        x_t, wbf, buf_t, gate_t, C3);
    // qkv = depthwise3x3(t)                   px-major bf16 [px][576]
    dwconv3x3_px_kernel<<<dim3(NPX / 128, 9), blk, 0, stream>>>(
        buf_t, w_depth, buf_qkv);
    // att_t = attention(qkv, rpb)             px-major bf16
    attention_mfma_kernel<<<dim3(H, HEADS, BATCH), blk, 0, stream>>>(
        buf_qkv, rpb, att_t);
    // y_t = (att_t @ w_pre) * gate_t          px-major bf16
    conv_mfma_kernel<2, 0, 3><<<dim3(768), blk, 0, stream>>>(
        att_t, w_pre_b, y_t, gate_t, C);
    // out = y_t @ w_out                       ch-major f32
    conv_mfma_kernel<0, 1, 3><<<dim3(768), blk, 0, stream>>>(
        y_t, w_out_b, out, nullptr, C);
}

// Round 4
// 284.366 us; speedup vs baseline: 1.2351x; 1.0744x over previous
//
#include <hip/hip_runtime.h>
#include <hip/hip_bf16.h>
#include <math.h>

#define BATCH 2
#define C 192
#define H 128
#define W 256
#define HEADS 6
#define HD 32
#define HW (H * W)      // 32768
#define C3 (3 * C)      // 576
#define NPX (BATCH * HW)  // 65536

typedef unsigned short ushort_t;
using bf16x8 = __attribute__((ext_vector_type(8))) short;
using f32x4  = __attribute__((ext_vector_type(4))) float;

static __device__ __forceinline__ float bfbits2f(ushort_t u) {
    return __uint_as_float(((unsigned)u) << 16);
}
static __device__ __forceinline__ ushort_t f2bfbits(float f) {
    __hip_bfloat16 h = __float2bfloat16(f);
    return *reinterpret_cast<ushort_t*>(&h);
}

// ---------------------------------------------------------------------------
// prep_w: fp32 -> bf16 weights; q-rows of w_qkv pre-scaled by 32^-0.5*log2(e)
// (softmax computed in base-2; exp2 saves the per-element ln2 multiply).
// Layout: w_qkv rows 0..575 | w_gate rows 576..767 | w_pre | w_out.
// ---------------------------------------------------------------------------
__global__ __launch_bounds__(256) void prep_w_kernel(
    const float* __restrict__ wq, const float* __restrict__ wg,
    const float* __restrict__ wp, const float* __restrict__ wo,
    ushort_t* __restrict__ dst)
{
    const int i = blockIdx.x * 256 + threadIdx.x;   // float4 index, < 55296
    const float* src; int off, base;
    if (i < 27648)      { src = wq; off = i;         base = 0; }
    else if (i < 36864) { src = wg; off = i - 27648; base = 110592; }
    else if (i < 46080) { src = wp; off = i - 36864; base = 147456; }
    else                { src = wo; off = i - 46080; base = 184320; }
    float4 v = ((const float4*)src)[off];
    if (i < 9216) {   // w_qkv rows 0..191 (the q projection)
        const float sc = 0.25503488f;   // 32^-0.5 * log2(e)
        v.x *= sc; v.y *= sc; v.z *= sc; v.w *= sc;
    }
    ushort4 o;
    o.x = f2bfbits(v.x); o.y = f2bfbits(v.y);
    o.z = f2bfbits(v.z); o.w = f2bfbits(v.w);
    *(ushort4*)(dst + base + off * 4) = o;
}

// ---------------------------------------------------------------------------
// transpose_x: x [B][192][HW] f32 -> x_t [B*HW][192] bf16 (pixel-major).
// ---------------------------------------------------------------------------
__global__ __launch_bounds__(256) void transpose_x_kernel(
    const float* __restrict__ x, ushort_t* __restrict__ xt)
{
    __shared__ uint Xs[64 * 97];   // 24.8 KB
    const int p0 = blockIdx.x * 64;
    const int b  = p0 >> 15, hw0 = p0 & (HW - 1);
    const int t  = threadIdx.x;

    {
        const int px = t & 63, g = t >> 6;
        const float* xb = x + (size_t)b * C * HW + hw0 + px;
#pragma unroll
        for (int i = 0; i < 24; ++i) {
            const int cp = g + i * 4;   // channel pair 0..95
            const float v0 = xb[(size_t)(2 * cp) * HW];
            const float v1 = xb[(size_t)(2 * cp + 1) * HW];
            Xs[px * 97 + cp] = (uint)f2bfbits(v0) | ((uint)f2bfbits(v1) << 16);
        }
    }
    __syncthreads();
    {
        const int px = t >> 2, grp = t & 3;
        uint* dst = (uint*)(xt + (size_t)(p0 + px) * C) + grp * 24;
        const uint* s = &Xs[px * 97 + grp * 24];
#pragma unroll
        for (int i = 0; i < 6; ++i) {
            uint4 u;
            u.x = s[i * 4 + 0]; u.y = s[i * 4 + 1];
            u.z = s[i * 4 + 2]; u.w = s[i * 4 + 3];
            *(uint4*)(dst + i * 4) = u;
        }
    }
}

// ---------------------------------------------------------------------------
// MFMA conv1x1 GEMM v5. Block: 4 waves; tile M=64(ch) x N=256(px), K=192.
// v3/v4 lesson: occupancy and load scheduling changes left throughput pinned
// at ~1.4 TB/s of WRITE bandwidth across three structures -> the wall is the
// scattered store pattern (ushort4 = 32B segments across 16 px rows per
// instruction). v5 fixes the WRITES: stage the 256px x 64ch bf16 result tile
// into LDS [256][72] (stride 72: rows 16B-aligned, banks even), then store
// with 8 lanes per px row -> each store instruction covers 8 x 128B
// contiguous segments (full HBM lines).
// Grid: lin = xcd + 8*(m + MT*pin); px-tile shares one XCD L2.
// MODE 0: none; 1: silu; 2: multiply by px-major gate; 3: fused qkv+gate
//   (MT=12: m 0..8 -> buf_t [px][576]; m 9..11 -> silu -> gate [px][192]).
// OUTKIND 0: px-major bf16 (LDS-coalesced); 1: ch-major f32 (final output,
//   64B-segment stores, unchanged).
// ---------------------------------------------------------------------------
template <int MODE, int OUTKIND, int MT>
__global__ __launch_bounds__(256, 2) void conv_mfma_kernel(
    const ushort_t* __restrict__ in_t, const ushort_t* __restrict__ w_bf,
    void* __restrict__ outp, ushort_t* __restrict__ gate, int ostride)
{
    const int lin = blockIdx.x;
    const int xcd = lin & 7;
    const int jj  = lin >> 3;
    const int pin = jj / MT;            // 0..31
    const int m   = jj - pin * MT;      // 0..MT-1
    const int m0  = m * 64;
    const int p0  = (xcd * 32 + pin) * 256;

    const int t  = threadIdx.x;
    const int wv = t >> 6, lane = t & 63, quad = lane >> 4, l16 = lane & 15;

    // As 64x200 (25.6KB) and Ls 256x72 (36.9KB) share this, by lifetime.
    __shared__ ushort_t smem[18432];
    ushort_t* As = smem;

    // ---- issue the wave's B panel (24x 16B gathers) ----
    const ushort_t* bp = in_t + (size_t)(p0 + wv * 64 + l16) * C + quad * 8;
    bf16x8 bF[6][4];
#pragma unroll
    for (int ks = 0; ks < 6; ++ks)
#pragma unroll
        for (int ct = 0; ct < 4; ++ct)
            bF[ks][ct] = *(const bf16x8*)(bp + (size_t)(ct * 16) * C + ks * 32);

    // ---- stage A (weights m0..m0+63 x 192) into LDS, padded to 200 ----
    {
        const int row = t >> 2, cg = (t & 3) * 48;
        const ushort_t* src = w_bf + (size_t)(m0 + row) * C + cg;
        ushort_t* dst = &As[row * 200 + cg];
#pragma unroll
        for (int i = 0; i < 6; ++i)
            *(bf16x8*)(dst + i * 8) = *(const bf16x8*)(src + i * 8);
    }
    __syncthreads();

    f32x4 acc[4][4];
#pragma unroll
    for (int rt = 0; rt < 4; ++rt)
#pragma unroll
        for (int ct = 0; ct < 4; ++ct) acc[rt][ct] = f32x4{0.f, 0.f, 0.f, 0.f};

    // ---- MFMA loop ----
#pragma unroll
    for (int ks = 0; ks < 6; ++ks) {
        bf16x8 aF[4];
#pragma unroll
        for (int rt = 0; rt < 4; ++rt)
            aF[rt] = *(const bf16x8*)&As[(rt * 16 + l16) * 200 + quad * 8 + ks * 32];
#pragma unroll
        for (int rt = 0; rt < 4; ++rt)
#pragma unroll
            for (int ct = 0; ct < 4; ++ct)
                acc[rt][ct] = __builtin_amdgcn_mfma_f32_16x16x32_bf16(
                    aF[rt], bF[ks][ct], acc[rt][ct], 0, 0, 0);
    }

    // ---- per-lane epilogue transforms ----
    const bool isg = (MODE == 3) && (m >= 9);   // gate block of fused kernel
    if (MODE == 1 || isg) {
#pragma unroll
        for (int rt = 0; rt < 4; ++rt)
#pragma unroll
            for (int ct = 0; ct < 4; ++ct) {
                f32x4 v = acc[rt][ct];
#pragma unroll
                for (int r = 0; r < 4; ++r)
                    v[r] = v[r] / (1.f + __expf(-v[r]));
                acc[rt][ct] = v;
            }
    }
    if (MODE == 2) {
#pragma unroll
        for (int rt = 0; rt < 4; ++rt)
#pragma unroll
            for (int ct = 0; ct < 4; ++ct) {
                const int px = p0 + wv * 64 + ct * 16 + l16;
                const int ch = m0 + rt * 16 + quad * 4;
                const ushort4 g = *(const ushort4*)(gate + (size_t)px * C + ch);
                f32x4 v = acc[rt][ct];
                v[0] *= bfbits2f(g.x); v[1] *= bfbits2f(g.y);
                v[2] *= bfbits2f(g.z); v[3] *= bfbits2f(g.w);
                acc[rt][ct] = v;
            }
    }

    if constexpr (OUTKIND == 0) {
        // ---- LDS-transposed coalesced store ----
        __syncthreads();                 // all As reads complete
        ushort_t* Ls = smem;             // [256][72]
#pragma unroll
        for (int rt = 0; rt < 4; ++rt)
#pragma unroll
            for (int ct = 0; ct < 4; ++ct) {
                const f32x4 v = acc[rt][ct];
                ushort4 o;
                o.x = f2bfbits(v[0]); o.y = f2bfbits(v[1]);
                o.z = f2bfbits(v[2]); o.w = f2bfbits(v[3]);
                *(ushort4*)&Ls[(wv * 64 + ct * 16 + l16) * 72 +
                               rt * 16 + quad * 4] = o;
            }
        __syncthreads();

        ushort_t* ob; int osr, chb;
        if constexpr (MODE == 3) {
            ob  = isg ? gate : (ushort_t*)outp;
            osr = isg ? C : C3;
            chb = isg ? m0 - C3 : m0;
        } else {
            ob = (ushort_t*)outp; osr = ostride; chb = m0;
        }
        const int pxl = t >> 3, c8 = (t & 7) * 8;
#pragma unroll
        for (int r = 0; r < 8; ++r) {
            const int px = r * 32 + pxl;
            const bf16x8 v = *(const bf16x8*)&Ls[px * 72 + c8];
            *(bf16x8*)(ob + (size_t)(p0 + px) * osr + chb + c8) = v;
        }
    } else {
        // channel-major f32 [B][192][HW] (final output); 64B-line segments.
        const int bb = p0 >> 15;
        const int hwb = (p0 & (HW - 1)) + wv * 64;
        float* ob = (float*)outp + ((size_t)bb * C + m0) * HW + hwb;
#pragma unroll
        for (int rt = 0; rt < 4; ++rt)
#pragma unroll
            for (int ct = 0; ct < 4; ++ct) {
                const f32x4 v = acc[rt][ct];
#pragma unroll
                for (int r = 0; r < 4; ++r)
                    ob[(size_t)(rt * 16 + quad * 4 + r) * HW + ct * 16 + l16] = v[r];
            }
    }
}

// ---------------------------------------------------------------------------
// depthwise 3x3, pixel-major. v2: stores via LDS transpose (128px x 64ch tile)
// so each store instruction is 8 x 128B contiguous segments (was 16B scatter).
// ---------------------------------------------------------------------------
__global__ __launch_bounds__(256) void dwconv3x3_px_kernel(
    const ushort_t* __restrict__ tin, const float* __restrict__ wd,
    ushort_t* __restrict__ out)
{
    __shared__ float wloc[576];
    __shared__ ushort_t Ld[128 * 72];   // 18.4 KB
    const int cb  = blockIdx.y;
    const int tid = threadIdx.x;
    if (tid < 144)
        *(float4*)&wloc[tid * 4] = *(const float4*)(wd + cb * 576 + tid * 4);
    __syncthreads();

    const int chloc = (tid & 7) * 8;
    const int pxl0 = (tid >> 3) * 4;               // local px 0..124
    const int px = blockIdx.x * 128 + pxl0;
    const int x0 = px & (W - 1);
    const int y  = (px >> 8) & (H - 1);

    const ushort_t* tb = tin + (size_t)px * C3 + cb * 64 + chloc;

    float acc[4][8];
#pragma unroll
    for (int i = 0; i < 4; ++i)
#pragma unroll
        for (int k = 0; k < 8; ++k) acc[i][k] = 0.f;

#pragma unroll
    for (int dy = -1; dy <= 1; ++dy) {
        const int yy = y + dy;
        if (yy < 0 || yy >= H) continue;
        const ushort_t* rp = tb + (ptrdiff_t)dy * W * C3;

        float f[6][8];
#pragma unroll
        for (int d = 0; d < 6; ++d) {
            const int xx = x0 + d - 1;
            if (xx < 0 || xx >= W) {
#pragma unroll
                for (int k = 0; k < 8; ++k) f[d][k] = 0.f;
            } else {
                const bf16x8 v = *(const bf16x8*)(rp + (ptrdiff_t)(d - 1) * C3);
#pragma unroll
                for (int k = 0; k < 8; ++k) f[d][k] = bfbits2f((ushort_t)v[k]);
            }
        }
#pragma unroll
        for (int k = 0; k < 8; ++k) {
            const float* wk = &wloc[(chloc + k) * 9 + (dy + 1) * 3];
            const float w0 = wk[0], w1 = wk[1], w2 = wk[2];
#pragma unroll
            for (int i = 0; i < 4; ++i)
                acc[i][k] += f[i][k] * w0 + f[i + 1][k] * w1 + f[i + 2][k] * w2;
        }
    }

    // stage to LDS [128][72]
#pragma unroll
    for (int i = 0; i < 4; ++i) {
        bf16x8 o;
#pragma unroll
        for (int k = 0; k < 8; ++k) o[k] = (short)f2bfbits(acc[i][k]);
        *(bf16x8*)&Ld[(pxl0 + i) * 72 + chloc] = o;
    }
    __syncthreads();

    // coalesced store: 8 lanes per px row (128B contiguous per px)
    const int pxl = tid >> 3, c8 = (tid & 7) * 8;
#pragma unroll
    for (int r = 0; r < 4; ++r) {
        const int p = r * 32 + pxl;
        const bf16x8 v = *(const bf16x8*)&Ld[p * 72 + c8];
        *(bf16x8*)(out + (size_t)(blockIdx.x * 128 + p) * C3 + cb * 64 + c8) = v;
    }
}

// ---------------------------------------------------------------------------
// MFMA attention v3: as v2 plus coalesced final store (4 lanes per px row ->
// 64B contiguous segments instead of 16B scatter).
// ---------------------------------------------------------------------------
__global__ __launch_bounds__(256, 4) void attention_mfma_kernel(
    const ushort_t* __restrict__ qkv, const float* __restrict__ rpb,
    ushort_t* __restrict__ att)
{
    const int y    = blockIdx.x;
    const int head = blockIdx.y;
    const int b    = blockIdx.z;
    const int t    = threadIdx.x;
    const int wv   = t >> 6;
    const int lane = t & 63;
    const int quad = lane >> 4;
    const int l16  = lane & 15;

    __shared__ __align__(16) char smem[39424];
    ushort_t* Vt = (ushort_t*)smem;               // [32][264]  = 16896 B
    ushort_t* Pb = (ushort_t*)(smem + 16896);     // [4][64][40]= 20480 B
    ushort_t* rb = (ushort_t*)(smem + 37376);     // [2][512]   =  2048 B
    float*    Ol = (float*)smem;                  // [32][257] epilogue overlay

    const size_t rowbase = ((size_t)b * HW + (size_t)y * W) * C3;
    const ushort_t* qbase = qkv + rowbase + head * HD + quad * 8;
    const ushort_t* kbase = qbase + C;

    // ---- stage V transposed into LDS; build base-2 rpb table (2 copies) ----
    {
        const ushort_t* rowp = qkv + rowbase + (size_t)t * C3 + head * HD;
        bf16x8 vfr[4];
#pragma unroll
        for (int g = 0; g < 4; ++g)
            vfr[g] = *(const bf16x8*)(rowp + 2 * C + g * 8);
#pragma unroll
        for (int g = 0; g < 4; ++g)
#pragma unroll
            for (int k = 0; k < 8; ++k)
                Vt[(g * 8 + k) * 264 + t] = (ushort_t)vfr[g][k];
    }
    {
        const float LOG2E = 1.4426950408889634f;
#pragma unroll
        for (int s2 = 0; s2 < 2; ++s2)
#pragma unroll
            for (int pp = 0; pp < 2; ++pp) {
                const int k = pp * 256 + t;
                const int src = k + s2;
                rb[s2 * 512 + k] =
                    f2bfbits(src <= 510 ? rpb[src * HEADS + head] * LOG2E : 0.f);
            }
    }

    // Q fragments (B-operand layout) direct from global; first K fragment.
    bf16x8 aQ[4];
#pragma unroll
    for (int rt = 0; rt < 4; ++rt)
        aQ[rt] = *(const bf16x8*)(qbase + (size_t)(wv * 64 + rt * 16 + l16) * C3);
    bf16x8 bK = *(const bf16x8*)(kbase + (size_t)l16 * C3);

    __syncthreads();

    ushort_t* PbW = Pb + wv * 2560;
    float lsum[4] = {0.f, 0.f, 0.f, 0.f};
    f32x4 o_acc[4][2];
#pragma unroll
    for (int rt = 0; rt < 4; ++rt)
#pragma unroll
        for (int ct = 0; ct < 2; ++ct)
            o_acc[rt][ct] = f32x4{0.f, 0.f, 0.f, 0.f};

    const int ibase = wv * 64 + l16 + 255 - quad * 4;

    for (int c2 = 0; c2 < 8; ++c2) {
#pragma unroll
        for (int half = 0; half < 2; ++half) {
            const int n  = c2 * 2 + half;
            const int nn = (n < 15) ? n + 1 : 15;
            const bf16x8 bKn =
                *(const bf16x8*)(kbase + (size_t)(nn * 16 + l16) * C3);
#pragma unroll
            for (int rt = 0; rt < 4; ++rt) {
                // bias^T: idx = i - j + 255 = (ibase + rt*16 - n*16) - reg
                const int a  = ibase + rt * 16 - n * 16 - 3;  // 0..507
                const int s2 = a & 1;
                const uint* tp = (const uint*)(rb + s2 * 512 + (a - s2));
                const uint u0 = tp[0], u1 = tp[1];  // rpb2[a..a+3]
                f32x4 s;
                s[0] = __uint_as_float(u1 & 0xffff0000u);
                s[1] = __uint_as_float(u1 << 16);
                s[2] = __uint_as_float(u0 & 0xffff0000u);
                s[3] = __uint_as_float(u0 << 16);
                s = __builtin_amdgcn_mfma_f32_16x16x32_bf16(bK, aQ[rt], s, 0, 0, 0);
                const float p0 = __builtin_amdgcn_exp2f(s[0]);
                const float p1 = __builtin_amdgcn_exp2f(s[1]);
                const float p2 = __builtin_amdgcn_exp2f(s[2]);
                const float p3 = __builtin_amdgcn_exp2f(s[3]);
                lsum[rt] += (p0 + p1) + (p2 + p3);
                uint2 dd;
                dd.x = (uint)f2bfbits(p0) | ((uint)f2bfbits(p1) << 16);
                dd.y = (uint)f2bfbits(p2) | ((uint)f2bfbits(p3) << 16);
                *(uint2*)&PbW[(rt * 16 + l16) * 40 + half * 16 + quad * 4] = dd;
            }
            bK = bKn;
        }
        // PV for this 32-wide j block
#pragma unroll
        for (int rt = 0; rt < 4; ++rt) {
            const bf16x8 aP = *(const bf16x8*)&PbW[(rt * 16 + l16) * 40 + quad * 8];
#pragma unroll
            for (int ct = 0; ct < 2; ++ct) {
                const bf16x8 bV = *(const bf16x8*)
                    &Vt[(ct * 16 + l16) * 264 + c2 * 32 + quad * 8];
                o_acc[rt][ct] = __builtin_amdgcn_mfma_f32_16x16x32_bf16(
                    aP, bV, o_acc[rt][ct], 0, 0, 0);
            }
        }
    }

    // softmax denominators: lane-local partial + reduce across quads
    float linv[4];
#pragma unroll
    for (int rt = 0; rt < 4; ++rt) {
        float v = lsum[rt];
        v += __shfl_xor(v, 16);
        v += __shfl_xor(v, 32);
        linv[rt] = 1.f / v;
    }

    __syncthreads();   // all waves done with Vt/Pb -> overlay Ol
#pragma unroll
    for (int rt = 0; rt < 4; ++rt) {
        const int i = wv * 64 + rt * 16 + quad * 4;
        float sc[4];
#pragma unroll
        for (int reg = 0; reg < 4; ++reg)
            sc[reg] = __shfl(linv[rt], quad * 4 + reg);
#pragma unroll
        for (int ct = 0; ct < 2; ++ct) {
            const int c = ct * 16 + l16;
#pragma unroll
            for (int reg = 0; reg < 4; ++reg)
                Ol[c * 257 + i + reg] = o_acc[rt][ct][reg] * sc[reg];
        }
    }
    __syncthreads();

    // coalesced store: 4 lanes per px row (64B contiguous per px)
    const size_t orow = (size_t)b * HW + (size_t)y * W;
    const int pxl = t >> 2, part = t & 3;
#pragma unroll
    for (int r = 0; r < 4; ++r) {
        const int px = r * 64 + pxl;
        bf16x8 o;
#pragma unroll
        for (int k = 0; k < 8; ++k)
            o[k] = (short)f2bfbits(Ol[(part * 8 + k) * 257 + px]);
        *(bf16x8*)(att + (orow + px) * C + head * HD + part * 8) = o;
    }
}

// ---------------------------------------------------------------------------
extern "C" void kernel_launch(void* const* d_in, const int* in_sizes, int n_in,
                              void* d_out, int out_size, void* d_ws, size_t ws_size,
                              hipStream_t stream)
{
    const float* x       = (const float*)d_in[0];
    const float* rpb     = (const float*)d_in[1];
    const float* w_qkv   = (const float*)d_in[2];
    const float* w_depth = (const float*)d_in[3];
    const float* w_pre   = (const float*)d_in[4];
    const float* w_out   = (const float*)d_in[5];
    const float* w_gate  = (const float*)d_in[6];
    float* out = (float*)d_out;

    // workspace layout (176.7 MB), aliased by lifetime:
    char* wsb = (char*)d_ws;
    ushort_t* wbf      = (ushort_t*)wsb;           // qkv|gate|pre|out rows
    ushort_t* w_pre_b  = wbf + 147456;
    ushort_t* w_out_b  = wbf + 184320;
    ushort_t* gate_t   = (ushort_t*)(wsb + 524288u);
    ushort_t* buf_t    = (ushort_t*)(wsb + 25690112u);
    ushort_t* att_t    = (ushort_t*)(wsb + 25690112u);
    ushort_t* y_t      = (ushort_t*)(wsb + 50855936u);
    ushort_t* buf_qkv  = (ushort_t*)(wsb + 101187584u);
    ushort_t* x_t      = (ushort_t*)(wsb + 101187584u);

    dim3 blk(256);

    prep_w_kernel<<<dim3(216), blk, 0, stream>>>(w_qkv, w_gate, w_pre, w_out, wbf);
    transpose_x_kernel<<<dim3(NPX / 64), blk, 0, stream>>>(x, x_t);
    // fused: buf_t = x_t @ w_qkv (q pre-scaled), gate_t = silu(x_t @ w_gate)
    conv_mfma_kernel<3, 0, 12><<<dim3(3072), blk, 0, stream>>>(
        x_t, wbf, buf_t, gate_t, C3);
    // qkv = depthwise3x3(t)                   px-major bf16 [px][576]
    dwconv3x3_px_kernel<<<dim3(NPX / 128, 9), blk, 0, stream>>>(
        buf_t, w_depth, buf_qkv);
    // att_t = attention(qkv, rpb)             px-major bf16
    attention_mfma_kernel<<<dim3(H, HEADS, BATCH), blk, 0, stream>>>(
        buf_qkv, rpb, att_t);
    // y_t = (att_t @ w_pre) * gate_t          px-major bf16
    conv_mfma_kernel<2, 0, 3><<<dim3(768), blk, 0, stream>>>(
        att_t, w_pre_b, y_t, gate_t, C);
    // out = y_t @ w_out                       ch-major f32
    conv_mfma_kernel<0, 1, 3><<<dim3(768), blk, 0, stream>>>(
        y_t, w_out_b, out, nullptr, C);
}